// Round 16
// baseline (211.571 us; speedup 1.0000x reference)
//
#include <hip/hip_runtime.h>

typedef __attribute__((ext_vector_type(8))) __bf16 bf16x8;
typedef __attribute__((ext_vector_type(4))) float f32x4;

__device__ __forceinline__ unsigned short f2bf(float f) {
  __bf16 h = (__bf16)f;
  return __builtin_bit_cast(unsigned short, h);
}

__device__ __forceinline__ f32x4 mfma_bf16(bf16x8 a, bf16x8 b, f32x4 c) {
  return __builtin_amdgcn_mfma_f32_16x16x32_bf16(a, b, c, 0, 0, 0);
}

__device__ __forceinline__ void gload_lds16(const void* g, void* l) {
  __builtin_amdgcn_global_load_lds((const __attribute__((address_space(1))) void*)g,
                                   (__attribute__((address_space(3))) void*)l, 16, 0, 0);
}

// ---------------- conversion kernels ----------------

__global__ void cvt_f32_bf16(const float* __restrict__ in, unsigned short* __restrict__ out, int n4) {
  int i = blockIdx.x * blockDim.x + threadIdx.x;
  if (i < n4) {
    float4 v = reinterpret_cast<const float4*>(in)[i];
    ushort4 o;
    o.x = f2bf(v.x); o.y = f2bf(v.y); o.z = f2bf(v.z); o.w = f2bf(v.w);
    reinterpret_cast<ushort4*>(out)[i] = o;
  }
}

// 4 weight matrices in one launch: each 1048576 floats = 262144 float4
__global__ void cvt4_f32_bf16(const float* __restrict__ a, const float* __restrict__ b,
                              const float* __restrict__ c, const float* __restrict__ d,
                              unsigned short* __restrict__ oa, unsigned short* __restrict__ ob,
                              unsigned short* __restrict__ oc, unsigned short* __restrict__ od) {
  int i = blockIdx.x * blockDim.x + threadIdx.x;   // 1048576 total
  int which = i >> 18, j = i & 262143;
  const float* src = (which == 0) ? a : (which == 1) ? b : (which == 2) ? c : d;
  unsigned short* dst = (which == 0) ? oa : (which == 1) ? ob : (which == 2) ? oc : od;
  float4 v = reinterpret_cast<const float4*>(src)[j];
  ushort4 o;
  o.x = f2bf(v.x); o.y = f2bf(v.y); o.z = f2bf(v.z); o.w = f2bf(v.w);
  reinterpret_cast<ushort4*>(dst)[j] = o;
}

// er[128][2048] f32 -> ert[2048][128] bf16, LDS-tiled transpose
__global__ void er_transpose(const float* __restrict__ er, unsigned short* __restrict__ ert) {
  __shared__ float t[32][33];
  int w0 = blockIdx.x * 32, d0 = blockIdx.y * 32;
  int tx = threadIdx.x, ty = threadIdx.y;          // 32 x 8
#pragma unroll
  for (int i = 0; i < 4; ++i)
    t[ty + i * 8][tx] = er[(size_t)(d0 + ty + i * 8) * 2048 + w0 + tx];
  __syncthreads();
#pragma unroll
  for (int i = 0; i < 4; ++i)
    ert[(size_t)(w0 + ty + i * 8) * 128 + d0 + tx] = f2bf(t[tx][ty + i * 8]);
}

// ---------------- 3-in-1 QKV projection GEMM ----------------

__global__ __launch_bounds__(256, 1) void gemm_qkv3(
    const unsigned short* __restrict__ xb,
    const unsigned short* __restrict__ Wqb, const unsigned short* __restrict__ Wkb,
    const unsigned short* __restrict__ Wvb,
    const float* __restrict__ bq, const float* __restrict__ bk, const float* __restrict__ bvv,
    unsigned short* __restrict__ Qb, unsigned short* __restrict__ Kb,
    unsigned short* __restrict__ Vtb)
{
  __shared__ __align__(16) char lds[131072];   // buf: A@0 BQ@16K BK@32K BV@48K, x2

  const int tid = threadIdx.x;
  const int lane = tid & 63, wid = tid >> 6;
  const int lr = lane & 15, lq = lane >> 4;
  const int wr = wid >> 1, wc = wid & 1;
  const int i0 = blockIdx.x * 128, j0 = blockIdx.y * 128;

  f32x4 aQ[4][4] = {}, aK[4][4] = {}, aV[4][4] = {};

  int ldso[4];
  const char *asrc[4], *qsrc[4], *ksrc[4], *vsrc[4];
#pragma unroll
  for (int p = 0; p < 4; ++p) {
    int L = p * 4096 + tid * 16;
    int row = L >> 7, colb = L & 127;
    int sc = colb ^ ((row & 7) << 4);
    ldso[p] = L;
    asrc[p] = (const char*)xb  + (size_t)(i0 + row) * 2048 + sc;
    qsrc[p] = (const char*)Wqb + (size_t)(j0 + row) * 2048 + sc;
    ksrc[p] = (const char*)Wkb + (size_t)(j0 + row) * 2048 + sc;
    vsrc[p] = (const char*)Wvb + (size_t)(j0 + row) * 2048 + sc;
  }

#pragma unroll
  for (int p = 0; p < 4; ++p) gload_lds16(asrc[p], lds + ldso[p]);
#pragma unroll
  for (int p = 0; p < 4; ++p) gload_lds16(qsrc[p], lds + 16384 + ldso[p]);
#pragma unroll
  for (int p = 0; p < 4; ++p) gload_lds16(ksrc[p], lds + 32768 + ldso[p]);
#pragma unroll
  for (int p = 0; p < 4; ++p) gload_lds16(vsrc[p], lds + 49152 + ldso[p]);

  const int swz = (lr & 7) << 4;

  for (int kt = 0; kt < 16; ++kt) {
    char* cb = lds + (kt & 1) * 65536;
    char* nb = lds + ((kt + 1) & 1) * 65536;

    asm volatile("s_waitcnt vmcnt(0)" ::: "memory");
    __builtin_amdgcn_sched_barrier(0);
    __builtin_amdgcn_s_barrier();
    __builtin_amdgcn_sched_barrier(0);

    if (kt < 15) {
      const int k0b = (kt + 1) * 128;
#pragma unroll
      for (int p = 0; p < 4; ++p) gload_lds16(asrc[p] + k0b, nb + ldso[p]);
#pragma unroll
      for (int p = 0; p < 4; ++p) gload_lds16(qsrc[p] + k0b, nb + 16384 + ldso[p]);
#pragma unroll
      for (int p = 0; p < 4; ++p) gload_lds16(ksrc[p] + k0b, nb + 32768 + ldso[p]);
#pragma unroll
      for (int p = 0; p < 4; ++p) gload_lds16(vsrc[p] + k0b, nb + 49152 + ldso[p]);
    }
    __builtin_amdgcn_sched_barrier(0);

#pragma unroll
    for (int kk = 0; kk < 2; ++kk) {
      const int coff = (kk * 64 + lq * 16) ^ swz;
      bf16x8 af[4];
#pragma unroll
      for (int m = 0; m < 4; ++m)
        af[m] = *(const bf16x8*)(cb + (wr * 64 + m * 16 + lr) * 128 + coff);
      bf16x8 bq_[4], bk_[4], bv_[4];
#pragma unroll
      for (int n = 0; n < 4; ++n) {
        const int rb = (wc * 64 + n * 16 + lr) * 128 + coff;
        bq_[n] = *(const bf16x8*)(cb + 16384 + rb);
        bk_[n] = *(const bf16x8*)(cb + 32768 + rb);
        bv_[n] = *(const bf16x8*)(cb + 49152 + rb);
      }
      __builtin_amdgcn_s_setprio(1);
#pragma unroll
      for (int m = 0; m < 4; ++m)
#pragma unroll
        for (int n = 0; n < 4; ++n) {
          aQ[m][n] = mfma_bf16(af[m], bq_[n], aQ[m][n]);
          aK[m][n] = mfma_bf16(af[m], bk_[n], aK[m][n]);
          aV[m][n] = mfma_bf16(af[m], bv_[n], aV[m][n]);
        }
      __builtin_amdgcn_s_setprio(0);
    }
  }

  float vbq[4], vbk[4], vbv[4];
#pragma unroll
  for (int n = 0; n < 4; ++n) {
    int gj = j0 + wc * 64 + n * 16 + lr;
    vbq[n] = bq[gj]; vbk[n] = bk[gj]; vbv[n] = bvv[gj];
  }

#pragma unroll
  for (int m = 0; m < 4; ++m)
#pragma unroll
    for (int n = 0; n < 4; ++n)
#pragma unroll
      for (int r = 0; r < 4; ++r) {
        int gi = i0 + wr * 64 + m * 16 + lq * 4 + r;
        int gj = j0 + wc * 64 + n * 16 + lr;
        Qb[(size_t)gi * 1024 + gj] = f2bf(aQ[m][n][r] + vbq[n]);
        Kb[(size_t)gi * 1024 + gj] = f2bf(aK[m][n][r] + vbk[n]);
      }

  __syncthreads();
  unsigned short* lds16 = (unsigned short*)lds;
#pragma unroll
  for (int m = 0; m < 4; ++m)
#pragma unroll
    for (int n = 0; n < 4; ++n)
#pragma unroll
      for (int r = 0; r < 4; ++r) {
        int il = wr * 64 + m * 16 + lq * 4 + r;
        int jl = wc * 64 + n * 16 + lr;
        lds16[jl * 132 + il] = f2bf(aV[m][n][r] + vbv[n]);
      }
  __syncthreads();
  {
    const int b = i0 >> 11, w0 = i0 & 2047, bd = j0 >> 7;
    for (int idx = tid; idx < 16384; idx += 256) {
      int dl = idx >> 7, wl = idx & 127;
      Vtb[(size_t)((b * 8 + bd) * 128 + dl) * 2048 + w0 + wl] = lds16[dl * 132 + wl];
    }
  }
}

// ---------------- Wo GEMM ----------------

__global__ __launch_bounds__(256, 2) void gemm_bt(
    const unsigned short* __restrict__ A,
    const unsigned short* __restrict__ Bt,
    const float* __restrict__ bias,
    float* __restrict__ C)
{
  __shared__ __align__(16) char base[32768];   // A0@0 B0@8192 A1@16384 B1@24576

  const int tid = threadIdx.x;
  const int lane = tid & 63, wid = tid >> 6;
  const int lr = lane & 15, lq = lane >> 4;
  const int wr = wid >> 1, wc = wid & 1;
  const int i0 = blockIdx.x * 128, j0 = blockIdx.y * 128;

  f32x4 acc[4][4] = {};

  const char* Abase = (const char*)A + (size_t)(i0 + (tid >> 2)) * 2048 + ((tid & 3) << 4);
  const char* Bbase = (const char*)Bt + (size_t)(j0 + (tid >> 2)) * 2048 + ((tid & 3) << 4);

  gload_lds16(Abase,             base + tid * 16);
  gload_lds16(Abase + 64 * 2048, base + 4096 + tid * 16);
  gload_lds16(Bbase,             base + 8192 + tid * 16);
  gload_lds16(Bbase + 64 * 2048, base + 12288 + tid * 16);

  for (int kt = 0; kt < 32; ++kt) {
    char* cbuf = base + (kt & 1) * 16384;
    char* nbuf = base + ((kt + 1) & 1) * 16384;

    asm volatile("s_waitcnt vmcnt(0)" ::: "memory");
    __builtin_amdgcn_sched_barrier(0);
    __builtin_amdgcn_s_barrier();
    __builtin_amdgcn_sched_barrier(0);

    if (kt < 31) {
      const int k0b = (kt + 1) * 64;
      gload_lds16(Abase + k0b,             nbuf + tid * 16);
      gload_lds16(Abase + k0b + 64 * 2048, nbuf + 4096 + tid * 16);
      gload_lds16(Bbase + k0b,             nbuf + 8192 + tid * 16);
      gload_lds16(Bbase + k0b + 64 * 2048, nbuf + 12288 + tid * 16);
    }
    __builtin_amdgcn_sched_barrier(0);

    bf16x8 af[4], bfr[4];
#pragma unroll
    for (int m = 0; m < 4; ++m)
      af[m] = *(const bf16x8*)(cbuf + (wr * 64 + m * 16 + lr) * 64 + lq * 16);
#pragma unroll
    for (int n = 0; n < 4; ++n)
      bfr[n] = *(const bf16x8*)(cbuf + 8192 + (wc * 64 + n * 16 + lr) * 64 + lq * 16);
    __builtin_amdgcn_s_setprio(1);
#pragma unroll
    for (int m = 0; m < 4; ++m)
#pragma unroll
      for (int n = 0; n < 4; ++n)
        acc[m][n] = mfma_bf16(af[m], bfr[n], acc[m][n]);
    __builtin_amdgcn_s_setprio(0);
  }

  float bv[4];
#pragma unroll
  for (int n = 0; n < 4; ++n) bv[n] = bias[j0 + wc * 64 + n * 16 + lr];
#pragma unroll
  for (int m = 0; m < 4; ++m)
#pragma unroll
    for (int n = 0; n < 4; ++n)
#pragma unroll
      for (int r = 0; r < 4; ++r) {
        int gi = i0 + wr * 64 + m * 16 + lq * 4 + r;
        int gj = j0 + wc * 64 + n * 16 + lr;
        C[(size_t)gi * 1024 + gj] = acc[m][n][r] + bv[n];
      }
}

// ---------------- fused attention ----------------
// R15 pipeline (counted vmcnt 36/40, KQ-prefetch-before-stores) with the wave
// decomposition changed from 8Mx1N (16 rows x 128 cols each) to 4Mx2N
// (32 rows x 64 cols each): every K/Q/V B-panel read feeds 2 row-fragments
// and covers half the columns -> LDS b128 reads/iter/CU drop ~800 -> ~448.
// Cost: online softmax needs cross-wave (max,sum) exchange via 2KB LDS +
// 2 barriers; the sum barrier also closes the V-visibility race pre-PV.

__global__ __launch_bounds__(512) void attn_fused(
    const unsigned short* __restrict__ Qb,
    const unsigned short* __restrict__ Kb,
    const unsigned short* __restrict__ Vt,
    const unsigned short* __restrict__ ErT,
    float* __restrict__ a_out,
    unsigned short* __restrict__ ctx)
{
  __shared__ __align__(16) char Klb[32768];  // K[kj] [128][256B] swz
  __shared__ __align__(16) char Qlb[32768];  // Q[kj] [128][256B] swz
  __shared__ __align__(16) char Vlb[32768];  // Vt    [128][256B] swz
  __shared__ __align__(16) char Plb[32768];  // P     [128][256B] swz
  __shared__ float Xm[128][2];               // partial row-max exchange
  __shared__ float Xs[128][2];               // partial row-sum exchange

  const int bb = blockIdx.x;                 // b*8+band
  const int bd = bb & 7, b = bb >> 3;
  const int qi0 = blockIdx.y * 128;
  const int tid = threadIdx.x, wid = tid >> 6, lane = tid & 63;
  const int lr = lane & 15, lq = lane >> 4;
  const int wr = wid >> 1, wc = wid & 1;     // 4M x 2N wave grid

  // persistent A-fragments: Q[qi] and ErT[qi], 2 row-fragments x 4 k-slices
  bf16x8 qf[2][4], ef[2][4];
#pragma unroll
  for (int fr = 0; fr < 2; ++fr) {
    const unsigned short* Qrow =
        Qb + (size_t)(b * 2048 + qi0 + wr * 32 + fr * 16 + lr) * 1024 + bd * 128;
    const unsigned short* Erow = ErT + (size_t)(qi0 + wr * 32 + fr * 16 + lr) * 128;
#pragma unroll
    for (int kk = 0; kk < 4; ++kk) {
      qf[fr][kk] = *(const bf16x8*)(Qrow + kk * 32 + lq * 8);
      ef[fr][kk] = *(const bf16x8*)(Erow + kk * 32 + lq * 8);
    }
  }

  int ldso[4];
  const char *ksrc[4], *qsrc[4], *vsrc[4];
#pragma unroll
  for (int p = 0; p < 4; ++p) {
    int L = p * 8192 + tid * 16;
    int row = L >> 8, cs = L & 255;
    int sc = cs ^ ((row & 7) << 4);
    ldso[p] = L;
    ksrc[p] = (const char*)Kb + ((size_t)(b * 2048 + row) * 1024 + bd * 128) * 2 + sc;
    qsrc[p] = (const char*)Qb + ((size_t)(b * 2048 + row) * 1024 + bd * 128) * 2 + sc;
    vsrc[p] = (const char*)Vt + ((size_t)(bb * 128 + row) * 2048) * 2 + sc;
  }

  // prologue: stage tile 0, drain once
#pragma unroll
  for (int p = 0; p < 4; ++p) gload_lds16(ksrc[p], Klb + ldso[p]);
#pragma unroll
  for (int p = 0; p < 4; ++p) gload_lds16(qsrc[p], Qlb + ldso[p]);
#pragma unroll
  for (int p = 0; p < 4; ++p) gload_lds16(vsrc[p], Vlb + ldso[p]);
  asm volatile("s_waitcnt vmcnt(0)" ::: "memory");
  __builtin_amdgcn_sched_barrier(0);

  f32x4 oacc[2][4] = {};
  float M[2][4], Ls[2][4];
#pragma unroll
  for (int fr = 0; fr < 2; ++fr)
#pragma unroll
    for (int r = 0; r < 4; ++r) { M[fr][r] = -1e30f; Ls[fr][r] = 0.f; }

  float* abase = a_out + (size_t)bb * 2048 * 2048;

  for (int kt = 0; kt < 16; ++kt) {
    const int kj0 = kt * 128;
    const size_t nkq = (size_t)((kt + 1) & 15) * 262144;
    const size_t nv = (size_t)((kt + 1) & 15) * 256;

    // own KQ(t) landed (32 stores + 4 V may remain); rendezvous
    asm volatile("s_waitcnt vmcnt(36)" ::: "memory");
    __builtin_amdgcn_sched_barrier(0);
    __builtin_amdgcn_s_barrier();
    __builtin_amdgcn_sched_barrier(0);

    // S = Q·K^T + ErT·Qk^T over this wave's 64 kv cols; B-reads feed both frs
    f32x4 sacc[2][4] = {};
    __builtin_amdgcn_s_setprio(1);
#pragma unroll
    for (int kk = 0; kk < 4; ++kk) {
#pragma unroll
      for (int nf = 0; nf < 4; ++nf) {
        const int row = wc * 64 + nf * 16 + lr;
        const int coff = (kk * 64 + lq * 16) ^ ((row & 7) << 4);
        bf16x8 kf = *(const bf16x8*)(Klb + row * 256 + coff);
        sacc[0][nf] = mfma_bf16(qf[0][kk], kf, sacc[0][nf]);
        sacc[1][nf] = mfma_bf16(qf[1][kk], kf, sacc[1][nf]);
        bf16x8 qkf = *(const bf16x8*)(Qlb + row * 256 + coff);
        sacc[0][nf] = mfma_bf16(ef[0][kk], qkf, sacc[0][nf]);
        sacc[1][nf] = mfma_bf16(ef[1][kk], qkf, sacc[1][nf]);
      }
    }
    __builtin_amdgcn_s_setprio(0);

    __builtin_amdgcn_sched_barrier(0);
    __builtin_amdgcn_s_barrier();        // all waves done reading Klb/Qlb
    __builtin_amdgcn_sched_barrier(0);

    // issue KQ(t+1) first (keeps stores younger in FIFO)
#pragma unroll
    for (int p = 0; p < 4; ++p) gload_lds16(ksrc[p] + nkq, Klb + ldso[p]);
#pragma unroll
    for (int p = 0; p < 4; ++p) gload_lds16(qsrc[p] + nkq, Qlb + ldso[p]);
    __builtin_amdgcn_sched_barrier(0);

    // scale and emit `a` (pair of wc waves covers 512B of each row)
#pragma unroll
    for (int fr = 0; fr < 2; ++fr) {
#pragma unroll
      for (int nf = 0; nf < 4; ++nf)
#pragma unroll
        for (int r = 0; r < 4; ++r) sacc[fr][nf][r] *= 0.03125f;
      const int qrow_base = qi0 + wr * 32 + fr * 16 + lq * 4;
#pragma unroll
      for (int nf = 0; nf < 4; ++nf)
#pragma unroll
        for (int r = 0; r < 4; ++r)
          abase[(size_t)(qrow_base + r) * 2048 + kj0 + wc * 64 + nf * 16 + lr] =
              sacc[fr][nf][r];
    }
    __builtin_amdgcn_sched_barrier(0);

    // partial row-max over own 64 cols, exchange with pair wave
    float rmax[2][4];
#pragma unroll
    for (int fr = 0; fr < 2; ++fr)
#pragma unroll
      for (int r = 0; r < 4; ++r) {
        float m0 = fmaxf(fmaxf(sacc[fr][0][r], sacc[fr][1][r]),
                         fmaxf(sacc[fr][2][r], sacc[fr][3][r]));
        m0 = fmaxf(m0, __shfl_xor(m0, 1));
        m0 = fmaxf(m0, __shfl_xor(m0, 2));
        m0 = fmaxf(m0, __shfl_xor(m0, 4));
        m0 = fmaxf(m0, __shfl_xor(m0, 8));
        rmax[fr][r] = m0;
        if (lr == 0) Xm[wr * 32 + fr * 16 + lq * 4 + r][wc] = m0;
      }
    __builtin_amdgcn_s_barrier();        // Xm ready
#pragma unroll
    for (int fr = 0; fr < 2; ++fr)
#pragma unroll
      for (int r = 0; r < 4; ++r)
        rmax[fr][r] = fmaxf(rmax[fr][r], Xm[wr * 32 + fr * 16 + lq * 4 + r][wc ^ 1]);

    // defer-max vote (pair waves see identical rows -> consistent decisions)
    bool small = true;
#pragma unroll
    for (int fr = 0; fr < 2; ++fr)
#pragma unroll
      for (int r = 0; r < 4; ++r) small &= (rmax[fr][r] - M[fr][r] <= 8.f);
    unsigned long long vote = __ballot(small);
    if (vote != ~0ull) {                 // rescale path
#pragma unroll
      for (int fr = 0; fr < 2; ++fr) {
        float scl[4];
#pragma unroll
        for (int r = 0; r < 4; ++r) {
          float Mn = fmaxf(M[fr][r], rmax[fr][r]);
          scl[r] = __expf(M[fr][r] - Mn);
          M[fr][r] = Mn;
          Ls[fr][r] *= scl[r];
        }
#pragma unroll
        for (int dn = 0; dn < 4; ++dn)
#pragma unroll
          for (int r = 0; r < 4; ++r) oacc[fr][dn][r] *= scl[r];
      }
    }

    // exp, partial sums, P -> LDS; stash partial sums for exchange
    float rsum[2][4];
#pragma unroll
    for (int fr = 0; fr < 2; ++fr) {
#pragma unroll
      for (int r = 0; r < 4; ++r) rsum[fr][r] = 0.f;
#pragma unroll
      for (int nf = 0; nf < 4; ++nf)
#pragma unroll
        for (int r = 0; r < 4; ++r) {
          float pv = __expf(sacc[fr][nf][r] - M[fr][r]);
          sacc[fr][nf][r] = pv;
          rsum[fr][r] += pv;
        }
      const int prow0 = wr * 32 + fr * 16 + lq * 4;
#pragma unroll
      for (int nf = 0; nf < 4; ++nf)
#pragma unroll
        for (int r = 0; r < 4; ++r) {
          const int row = prow0 + r;
          *(unsigned short*)(Plb + row * 256 +
              (((wc * 64 + nf * 16 + lr) * 2) ^ ((row & 7) << 4))) = f2bf(sacc[fr][nf][r]);
        }
#pragma unroll
      for (int r = 0; r < 4; ++r) {
        rsum[fr][r] += __shfl_xor(rsum[fr][r], 1);
        rsum[fr][r] += __shfl_xor(rsum[fr][r], 2);
        rsum[fr][r] += __shfl_xor(rsum[fr][r], 4);
        rsum[fr][r] += __shfl_xor(rsum[fr][r], 8);
        if (lr == 0) Xs[prow0 + r][wc] = rsum[fr][r];
      }
    }

    // own V(t) landed (KQ(t+1)+stores stay in flight); barrier makes ALL
    // waves' V, P and Xs visible before PV
    asm volatile("s_waitcnt vmcnt(40)" ::: "memory");
    __builtin_amdgcn_sched_barrier(0);
    __builtin_amdgcn_s_barrier();
    __builtin_amdgcn_sched_barrier(0);

#pragma unroll
    for (int fr = 0; fr < 2; ++fr)
#pragma unroll
      for (int r = 0; r < 4; ++r)
        Ls[fr][r] += rsum[fr][r] + Xs[wr * 32 + fr * 16 + lq * 4 + r][wc ^ 1];

    // O += P · V  (rows from pair-shared Plb, d-cols = this wave's 64)
    __builtin_amdgcn_s_setprio(1);
#pragma unroll
    for (int kk = 0; kk < 4; ++kk) {
      const int pr0 = wr * 32 + lr;
      const int pr1 = pr0 + 16;
      bf16x8 pf0 = *(const bf16x8*)(Plb + pr0 * 256 + ((kk * 64 + lq * 16) ^ ((pr0 & 7) << 4)));
      bf16x8 pf1 = *(const bf16x8*)(Plb + pr1 * 256 + ((kk * 64 + lq * 16) ^ ((pr1 & 7) << 4)));
#pragma unroll
      for (int dn = 0; dn < 4; ++dn) {
        const int vrow = wc * 64 + dn * 16 + lr;
        bf16x8 vf = *(const bf16x8*)(Vlb + vrow * 256 + ((kk * 64 + lq * 16) ^ ((vrow & 7) << 4)));
        oacc[0][dn] = mfma_bf16(pf0, vf, oacc[0][dn]);
        oacc[1][dn] = mfma_bf16(pf1, vf, oacc[1][dn]);
      }
    }
    __builtin_amdgcn_s_setprio(0);

    __builtin_amdgcn_sched_barrier(0);
    __builtin_amdgcn_s_barrier();        // all waves done reading Vlb/Plb
    __builtin_amdgcn_sched_barrier(0);
#pragma unroll
    for (int p = 0; p < 4; ++p) gload_lds16(vsrc[p] + nv, Vlb + ldso[p]);
    __builtin_amdgcn_sched_barrier(0);
  }

  // epilogue: ctx = O / L -> bf16 [b*2048+w][bd*128 + wc*64 + d]
#pragma unroll
  for (int fr = 0; fr < 2; ++fr) {
    const int qrow_base = b * 2048 + qi0 + wr * 32 + fr * 16 + lq * 4;
#pragma unroll
    for (int dn = 0; dn < 4; ++dn)
#pragma unroll
      for (int r = 0; r < 4; ++r) {
        float v = oacc[fr][dn][r] / Ls[fr][r];
        ctx[(size_t)(qrow_base + r) * 1024 + bd * 128 + wc * 64 + dn * 16 + lr] = f2bf(v);
      }
  }
}

// ---------------- launch ----------------

extern "C" void kernel_launch(void* const* d_in, const int* in_sizes, int n_in,
                              void* d_out, int out_size, void* d_ws, size_t ws_size,
                              hipStream_t stream) {
  const float* x  = (const float*)d_in[0];
  const float* Wq = (const float*)d_in[1];
  const float* bq = (const float*)d_in[2];
  const float* Wk = (const float*)d_in[3];
  const float* bk = (const float*)d_in[4];
  const float* Wv = (const float*)d_in[5];
  const float* bv = (const float*)d_in[6];
  const float* Wo = (const float*)d_in[7];
  const float* bo = (const float*)d_in[8];
  const float* er = (const float*)d_in[9];

  char* ws = (char*)d_ws;
  unsigned short* xb  = (unsigned short*)(ws + 0);          //  8 MB
  unsigned short* Wqb = (unsigned short*)(ws + 8388608);    //  2 MB
  unsigned short* Wkb = (unsigned short*)(ws + 10485760);   //  2 MB
  unsigned short* Wvb = (unsigned short*)(ws + 12582912);   //  2 MB
  unsigned short* Wob = (unsigned short*)(ws + 14680064);   //  2 MB
  unsigned short* Qb  = (unsigned short*)(ws + 16777216);   //  8 MB
  unsigned short* Kb  = (unsigned short*)(ws + 25165824);   //  8 MB
  unsigned short* Vtb = (unsigned short*)(ws + 33554432);   //  8 MB [16][128][2048]
  unsigned short* ctx = (unsigned short*)(ws + 41943040);   //  8 MB
  unsigned short* ert = (unsigned short*)(ws + 50331648);   //  0.5 MB [2048][128]

  float* a_out = (float*)d_out + 4194304;

  cvt_f32_bf16<<<dim3(4096), dim3(256), 0, stream>>>(x, xb, 1048576);
  cvt4_f32_bf16<<<dim3(4096), dim3(256), 0, stream>>>(Wq, Wk, Wv, Wo, Wqb, Wkb, Wvb, Wob);
  er_transpose<<<dim3(64, 4), dim3(32, 8), 0, stream>>>(er, ert);

  gemm_qkv3<<<dim3(32, 8), dim3(256), 0, stream>>>(xb, Wqb, Wkb, Wvb, bq, bk, bv,
                                                   Qb, Kb, Vtb);

  attn_fused<<<dim3(16, 16), dim3(512), 0, stream>>>(Qb, Kb, Vtb, ert, a_out, ctx);

  gemm_bt<<<dim3(32, 8), dim3(256), 0, stream>>>(ctx, Wob, bo, (float*)d_out);
}

// Round 17
// 177.499 us; speedup vs baseline: 1.1920x; 1.1920x over previous
//
#include <hip/hip_runtime.h>

typedef __attribute__((ext_vector_type(8))) __bf16 bf16x8;
typedef __attribute__((ext_vector_type(4))) float f32x4;

__device__ __forceinline__ unsigned short f2bf(float f) {
  __bf16 h = (__bf16)f;
  return __builtin_bit_cast(unsigned short, h);
}

__device__ __forceinline__ f32x4 mfma_bf16(bf16x8 a, bf16x8 b, f32x4 c) {
  return __builtin_amdgcn_mfma_f32_16x16x32_bf16(a, b, c, 0, 0, 0);
}

__device__ __forceinline__ void gload_lds16(const void* g, void* l) {
  __builtin_amdgcn_global_load_lds((const __attribute__((address_space(1))) void*)g,
                                   (__attribute__((address_space(3))) void*)l, 16, 0, 0);
}

// ---------------- conversion kernels ----------------

__global__ void cvt_f32_bf16(const float* __restrict__ in, unsigned short* __restrict__ out, int n4) {
  int i = blockIdx.x * blockDim.x + threadIdx.x;
  if (i < n4) {
    float4 v = reinterpret_cast<const float4*>(in)[i];
    ushort4 o;
    o.x = f2bf(v.x); o.y = f2bf(v.y); o.z = f2bf(v.z); o.w = f2bf(v.w);
    reinterpret_cast<ushort4*>(out)[i] = o;
  }
}

// 4 weight matrices in one launch: each 1048576 floats = 262144 float4
__global__ void cvt4_f32_bf16(const float* __restrict__ a, const float* __restrict__ b,
                              const float* __restrict__ c, const float* __restrict__ d,
                              unsigned short* __restrict__ oa, unsigned short* __restrict__ ob,
                              unsigned short* __restrict__ oc, unsigned short* __restrict__ od) {
  int i = blockIdx.x * blockDim.x + threadIdx.x;   // 1048576 total
  int which = i >> 18, j = i & 262143;
  const float* src = (which == 0) ? a : (which == 1) ? b : (which == 2) ? c : d;
  unsigned short* dst = (which == 0) ? oa : (which == 1) ? ob : (which == 2) ? oc : od;
  float4 v = reinterpret_cast<const float4*>(src)[j];
  ushort4 o;
  o.x = f2bf(v.x); o.y = f2bf(v.y); o.z = f2bf(v.z); o.w = f2bf(v.w);
  reinterpret_cast<ushort4*>(dst)[j] = o;
}

// er[128][2048] f32 -> ert[2048][128] bf16, LDS-tiled transpose
__global__ void er_transpose(const float* __restrict__ er, unsigned short* __restrict__ ert) {
  __shared__ float t[32][33];
  int w0 = blockIdx.x * 32, d0 = blockIdx.y * 32;
  int tx = threadIdx.x, ty = threadIdx.y;          // 32 x 8
#pragma unroll
  for (int i = 0; i < 4; ++i)
    t[ty + i * 8][tx] = er[(size_t)(d0 + ty + i * 8) * 2048 + w0 + tx];
  __syncthreads();
#pragma unroll
  for (int i = 0; i < 4; ++i)
    ert[(size_t)(w0 + ty + i * 8) * 128 + d0 + tx] = f2bf(t[tx][ty + i * 8]);
}

// ---------------- 3-in-1 QKV projection GEMM ----------------
// 512 threads = 8 waves (4M x 2N): 2 waves/SIMD for latency hiding (the 256-
// thread version ran 1 wave/SIMD -- zero TLP, fully exposed staging waits).
// Per wave: 32 rows x 64 cols, 3 matrices, 48 MFMA/iter. BK=64, 128KB dbuf,
// counted-vmcnt pipeline, XOR-swizzled tiles.

__global__ __launch_bounds__(512, 1) void gemm_qkv3(
    const unsigned short* __restrict__ xb,
    const unsigned short* __restrict__ Wqb, const unsigned short* __restrict__ Wkb,
    const unsigned short* __restrict__ Wvb,
    const float* __restrict__ bq, const float* __restrict__ bk, const float* __restrict__ bvv,
    unsigned short* __restrict__ Qb, unsigned short* __restrict__ Kb,
    unsigned short* __restrict__ Vtb)
{
  __shared__ __align__(16) char lds[131072];   // buf: A@0 BQ@16K BK@32K BV@48K, x2

  const int tid = threadIdx.x;
  const int lane = tid & 63, wid = tid >> 6;
  const int lr = lane & 15, lq = lane >> 4;
  const int wr = wid >> 1, wc = wid & 1;       // 4M x 2N wave grid
  const int i0 = blockIdx.x * 128, j0 = blockIdx.y * 128;

  f32x4 aQ[2][4] = {}, aK[2][4] = {}, aV[2][4] = {};

  // staging: each tile 16KB = 128 rows x 128B; 2 slots x 16B per thread/tile
  int ldso[2];
  const char *asrc[2], *qsrc[2], *ksrc[2], *vsrc[2];
#pragma unroll
  for (int p = 0; p < 2; ++p) {
    int L = p * 8192 + tid * 16;
    int row = L >> 7, colb = L & 127;
    int sc = colb ^ ((row & 7) << 4);
    ldso[p] = L;
    asrc[p] = (const char*)xb  + (size_t)(i0 + row) * 2048 + sc;
    qsrc[p] = (const char*)Wqb + (size_t)(j0 + row) * 2048 + sc;
    ksrc[p] = (const char*)Wkb + (size_t)(j0 + row) * 2048 + sc;
    vsrc[p] = (const char*)Wvb + (size_t)(j0 + row) * 2048 + sc;
  }

  // prologue: stage tile 0 into buf0 (8 loads in flight per thread)
#pragma unroll
  for (int p = 0; p < 2; ++p) gload_lds16(asrc[p], lds + ldso[p]);
#pragma unroll
  for (int p = 0; p < 2; ++p) gload_lds16(qsrc[p], lds + 16384 + ldso[p]);
#pragma unroll
  for (int p = 0; p < 2; ++p) gload_lds16(ksrc[p], lds + 32768 + ldso[p]);
#pragma unroll
  for (int p = 0; p < 2; ++p) gload_lds16(vsrc[p], lds + 49152 + ldso[p]);

  const int swz = (lr & 7) << 4;   // fragment-row swizzle: row&7 == lr&7

  for (int kt = 0; kt < 16; ++kt) {
    char* cb = lds + (kt & 1) * 65536;
    char* nb = lds + ((kt + 1) & 1) * 65536;

    asm volatile("s_waitcnt vmcnt(0)" ::: "memory");
    __builtin_amdgcn_sched_barrier(0);
    __builtin_amdgcn_s_barrier();
    __builtin_amdgcn_sched_barrier(0);

    if (kt < 15) {
      const int k0b = (kt + 1) * 128;
#pragma unroll
      for (int p = 0; p < 2; ++p) gload_lds16(asrc[p] + k0b, nb + ldso[p]);
#pragma unroll
      for (int p = 0; p < 2; ++p) gload_lds16(qsrc[p] + k0b, nb + 16384 + ldso[p]);
#pragma unroll
      for (int p = 0; p < 2; ++p) gload_lds16(ksrc[p] + k0b, nb + 32768 + ldso[p]);
#pragma unroll
      for (int p = 0; p < 2; ++p) gload_lds16(vsrc[p] + k0b, nb + 49152 + ldso[p]);
    }
    __builtin_amdgcn_sched_barrier(0);

#pragma unroll
    for (int kk = 0; kk < 2; ++kk) {
      const int coff = (kk * 64 + lq * 16) ^ swz;
      bf16x8 af[2];
#pragma unroll
      for (int m = 0; m < 2; ++m)
        af[m] = *(const bf16x8*)(cb + (wr * 32 + m * 16 + lr) * 128 + coff);
      bf16x8 bq_[4], bk_[4], bv_[4];
#pragma unroll
      for (int n = 0; n < 4; ++n) {
        const int rb = (wc * 64 + n * 16 + lr) * 128 + coff;
        bq_[n] = *(const bf16x8*)(cb + 16384 + rb);
        bk_[n] = *(const bf16x8*)(cb + 32768 + rb);
        bv_[n] = *(const bf16x8*)(cb + 49152 + rb);
      }
      __builtin_amdgcn_s_setprio(1);
#pragma unroll
      for (int m = 0; m < 2; ++m)
#pragma unroll
        for (int n = 0; n < 4; ++n) {
          aQ[m][n] = mfma_bf16(af[m], bq_[n], aQ[m][n]);
          aK[m][n] = mfma_bf16(af[m], bk_[n], aK[m][n]);
          aV[m][n] = mfma_bf16(af[m], bv_[n], aV[m][n]);
        }
      __builtin_amdgcn_s_setprio(0);
    }
  }

  float vbq[4], vbk[4], vbv[4];
#pragma unroll
  for (int n = 0; n < 4; ++n) {
    int gj = j0 + wc * 64 + n * 16 + lr;
    vbq[n] = bq[gj]; vbk[n] = bk[gj]; vbv[n] = bvv[gj];
  }

  // Q, K: direct bf16 row-major
#pragma unroll
  for (int m = 0; m < 2; ++m)
#pragma unroll
    for (int n = 0; n < 4; ++n)
#pragma unroll
      for (int r = 0; r < 4; ++r) {
        int gi = i0 + wr * 32 + m * 16 + lq * 4 + r;
        int gj = j0 + wc * 64 + n * 16 + lr;
        Qb[(size_t)gi * 1024 + gj] = f2bf(aQ[m][n][r] + vbq[n]);
        Kb[(size_t)gi * 1024 + gj] = f2bf(aK[m][n][r] + vbk[n]);
      }

  // V: band-transpose via LDS -> Vt[(b*8+bd)*128 + d][w]
  __syncthreads();
  unsigned short* lds16 = (unsigned short*)lds;
#pragma unroll
  for (int m = 0; m < 2; ++m)
#pragma unroll
    for (int n = 0; n < 4; ++n)
#pragma unroll
      for (int r = 0; r < 4; ++r) {
        int il = wr * 32 + m * 16 + lq * 4 + r;
        int jl = wc * 64 + n * 16 + lr;
        lds16[jl * 132 + il] = f2bf(aV[m][n][r] + vbv[n]);
      }
  __syncthreads();
  {
    const int b = i0 >> 11, w0 = i0 & 2047, bd = j0 >> 7;
    for (int idx = tid; idx < 16384; idx += 512) {
      int dl = idx >> 7, wl = idx & 127;
      Vtb[(size_t)((b * 8 + bd) * 128 + dl) * 2048 + w0 + wl] = lds16[dl * 132 + wl];
    }
  }
}

// ---------------- Wo GEMM ----------------

__global__ __launch_bounds__(256, 2) void gemm_bt(
    const unsigned short* __restrict__ A,
    const unsigned short* __restrict__ Bt,
    const float* __restrict__ bias,
    float* __restrict__ C)
{
  __shared__ __align__(16) char base[32768];   // A0@0 B0@8192 A1@16384 B1@24576

  const int tid = threadIdx.x;
  const int lane = tid & 63, wid = tid >> 6;
  const int lr = lane & 15, lq = lane >> 4;
  const int wr = wid >> 1, wc = wid & 1;
  const int i0 = blockIdx.x * 128, j0 = blockIdx.y * 128;

  f32x4 acc[4][4] = {};

  const char* Abase = (const char*)A + (size_t)(i0 + (tid >> 2)) * 2048 + ((tid & 3) << 4);
  const char* Bbase = (const char*)Bt + (size_t)(j0 + (tid >> 2)) * 2048 + ((tid & 3) << 4);

  gload_lds16(Abase,             base + tid * 16);
  gload_lds16(Abase + 64 * 2048, base + 4096 + tid * 16);
  gload_lds16(Bbase,             base + 8192 + tid * 16);
  gload_lds16(Bbase + 64 * 2048, base + 12288 + tid * 16);

  for (int kt = 0; kt < 32; ++kt) {
    char* cbuf = base + (kt & 1) * 16384;
    char* nbuf = base + ((kt + 1) & 1) * 16384;

    asm volatile("s_waitcnt vmcnt(0)" ::: "memory");
    __builtin_amdgcn_sched_barrier(0);
    __builtin_amdgcn_s_barrier();
    __builtin_amdgcn_sched_barrier(0);

    if (kt < 31) {
      const int k0b = (kt + 1) * 64;
      gload_lds16(Abase + k0b,             nbuf + tid * 16);
      gload_lds16(Abase + k0b + 64 * 2048, nbuf + 4096 + tid * 16);
      gload_lds16(Bbase + k0b,             nbuf + 8192 + tid * 16);
      gload_lds16(Bbase + k0b + 64 * 2048, nbuf + 12288 + tid * 16);
    }
    __builtin_amdgcn_sched_barrier(0);

    bf16x8 af[4], bfr[4];
#pragma unroll
    for (int m = 0; m < 4; ++m)
      af[m] = *(const bf16x8*)(cbuf + (wr * 64 + m * 16 + lr) * 64 + lq * 16);
#pragma unroll
    for (int n = 0; n < 4; ++n)
      bfr[n] = *(const bf16x8*)(cbuf + 8192 + (wc * 64 + n * 16 + lr) * 64 + lq * 16);
    __builtin_amdgcn_s_setprio(1);
#pragma unroll
    for (int m = 0; m < 4; ++m)
#pragma unroll
      for (int n = 0; n < 4; ++n)
        acc[m][n] = mfma_bf16(af[m], bfr[n], acc[m][n]);
    __builtin_amdgcn_s_setprio(0);
  }

  float bv[4];
#pragma unroll
  for (int n = 0; n < 4; ++n) bv[n] = bias[j0 + wc * 64 + n * 16 + lr];
#pragma unroll
  for (int m = 0; m < 4; ++m)
#pragma unroll
    for (int n = 0; n < 4; ++n)
#pragma unroll
      for (int r = 0; r < 4; ++r) {
        int gi = i0 + wr * 64 + m * 16 + lq * 4 + r;
        int gj = j0 + wc * 64 + n * 16 + lr;
        C[(size_t)gi * 1024 + gj] = acc[m][n][r] + bv[n];
      }
}

// ---------------- fused attention (R15 structure, verbatim) ----------------
// Counted-vmcnt pipeline: top vmcnt(36) drains only KQ(t); pre-PV vmcnt(40)
// drains only V(t); a-stores never waited on mid-loop (peak outstanding 44).

__global__ __launch_bounds__(512) void attn_fused(
    const unsigned short* __restrict__ Qb,
    const unsigned short* __restrict__ Kb,
    const unsigned short* __restrict__ Vt,
    const unsigned short* __restrict__ ErT,
    float* __restrict__ a_out,
    unsigned short* __restrict__ ctx)
{
  __shared__ __align__(16) char Klb[32768];  // K[kj] [128][256B] swz
  __shared__ __align__(16) char Qlb[32768];  // Q[kj] [128][256B] swz
  __shared__ __align__(16) char Vlb[32768];  // Vt    [128][256B] swz
  __shared__ __align__(16) char Plb[32768];  // P     [128][256B] swz

  const int bb = blockIdx.x;                 // b*8+band
  const int bd = bb & 7, b = bb >> 3;
  const int qi0 = blockIdx.y * 128;
  const int tid = threadIdx.x, wid = tid >> 6, lane = tid & 63;
  const int lr = lane & 15, lq = lane >> 4;

  bf16x8 qf[4], ef[4];
  {
    const unsigned short* Qrow = Qb + (size_t)(b * 2048 + qi0 + wid * 16 + lr) * 1024 + bd * 128;
    const unsigned short* Erow = ErT + (size_t)(qi0 + wid * 16 + lr) * 128;
#pragma unroll
    for (int kk = 0; kk < 4; ++kk) {
      qf[kk] = *(const bf16x8*)(Qrow + kk * 32 + lq * 8);
      ef[kk] = *(const bf16x8*)(Erow + kk * 32 + lq * 8);
    }
  }

  int ldso[4];
  const char *ksrc[4], *qsrc[4], *vsrc[4];
#pragma unroll
  for (int p = 0; p < 4; ++p) {
    int L = p * 8192 + tid * 16;
    int row = L >> 8, cs = L & 255;
    int sc = cs ^ ((row & 7) << 4);
    ldso[p] = L;
    ksrc[p] = (const char*)Kb + ((size_t)(b * 2048 + row) * 1024 + bd * 128) * 2 + sc;
    qsrc[p] = (const char*)Qb + ((size_t)(b * 2048 + row) * 1024 + bd * 128) * 2 + sc;
    vsrc[p] = (const char*)Vt + ((size_t)(bb * 128 + row) * 2048) * 2 + sc;
  }

  // prologue: stage tile 0, drain everything once (iter-0 safety)
#pragma unroll
  for (int p = 0; p < 4; ++p) gload_lds16(ksrc[p], Klb + ldso[p]);
#pragma unroll
  for (int p = 0; p < 4; ++p) gload_lds16(qsrc[p], Qlb + ldso[p]);
#pragma unroll
  for (int p = 0; p < 4; ++p) gload_lds16(vsrc[p], Vlb + ldso[p]);
  asm volatile("s_waitcnt vmcnt(0)" ::: "memory");
  __builtin_amdgcn_sched_barrier(0);

  f32x4 oacc[8] = {};
  float M[4], L[4];
#pragma unroll
  for (int r = 0; r < 4; ++r) { M[r] = -1e30f; L[r] = 0.f; }

  float* abase = a_out + (size_t)bb * 2048 * 2048;

  for (int kt = 0; kt < 16; ++kt) {
    const int kj0 = kt * 128;
    const size_t nkq = (size_t)((kt + 1) & 15) * 262144;
    const size_t nv = (size_t)((kt + 1) & 15) * 256;

    // own KQ(t) landed (32 stores + 4 V may remain in flight); rendezvous
    asm volatile("s_waitcnt vmcnt(36)" ::: "memory");
    __builtin_amdgcn_sched_barrier(0);
    __builtin_amdgcn_s_barrier();
    __builtin_amdgcn_sched_barrier(0);

    f32x4 sacc[8] = {};
    __builtin_amdgcn_s_setprio(1);
#pragma unroll
    for (int kk = 0; kk < 4; ++kk) {
#pragma unroll
      for (int nf = 0; nf < 8; ++nf) {
        const int row = nf * 16 + lr;
        bf16x8 kf = *(const bf16x8*)(Klb + row * 256 + ((kk * 64 + lq * 16) ^ ((row & 7) << 4)));
        sacc[nf] = mfma_bf16(qf[kk], kf, sacc[nf]);
      }
#pragma unroll
      for (int nf = 0; nf < 8; ++nf) {
        const int row = nf * 16 + lr;
        bf16x8 qkf = *(const bf16x8*)(Qlb + row * 256 + ((kk * 64 + lq * 16) ^ ((row & 7) << 4)));
        sacc[nf] = mfma_bf16(ef[kk], qkf, sacc[nf]);
      }
    }
    __builtin_amdgcn_s_setprio(0);

    __builtin_amdgcn_sched_barrier(0);
    __builtin_amdgcn_s_barrier();        // all waves done reading Klb/Qlb
    __builtin_amdgcn_sched_barrier(0);

    // issue KQ(t+1) FIRST (keeps stores younger in FIFO)
#pragma unroll
    for (int p = 0; p < 4; ++p) gload_lds16(ksrc[p] + nkq, Klb + ldso[p]);
#pragma unroll
    for (int p = 0; p < 4; ++p) gload_lds16(qsrc[p] + nkq, Qlb + ldso[p]);
    __builtin_amdgcn_sched_barrier(0);

    // scale and emit `a` (never waited on mid-loop)
#pragma unroll
    for (int nf = 0; nf < 8; ++nf)
#pragma unroll
      for (int r = 0; r < 4; ++r) sacc[nf][r] *= 0.03125f;
    {
      const int qrow_base = qi0 + wid * 16 + lq * 4;
#pragma unroll
      for (int nf = 0; nf < 8; ++nf)
#pragma unroll
        for (int r = 0; r < 4; ++r)
          abase[(size_t)(qrow_base + r) * 2048 + kj0 + nf * 16 + lr] = sacc[nf][r];
    }
    __builtin_amdgcn_sched_barrier(0);

    float rmax[4];
#pragma unroll
    for (int r = 0; r < 4; ++r) {
      float m0 = sacc[0][r];
#pragma unroll
      for (int nf = 1; nf < 8; ++nf) m0 = fmaxf(m0, sacc[nf][r]);
      m0 = fmaxf(m0, __shfl_xor(m0, 1));
      m0 = fmaxf(m0, __shfl_xor(m0, 2));
      m0 = fmaxf(m0, __shfl_xor(m0, 4));
      m0 = fmaxf(m0, __shfl_xor(m0, 8));
      rmax[r] = m0;
    }
    bool small = (rmax[0] - M[0] <= 8.f) & (rmax[1] - M[1] <= 8.f) &
                 (rmax[2] - M[2] <= 8.f) & (rmax[3] - M[3] <= 8.f);
    unsigned long long vote = __ballot(small);
    if (vote != ~0ull) {
      float scl[4];
#pragma unroll
      for (int r = 0; r < 4; ++r) {
        float Mn = fmaxf(M[r], rmax[r]);
        scl[r] = __expf(M[r] - Mn);
        M[r] = Mn;
        L[r] *= scl[r];
      }
#pragma unroll
      for (int dn = 0; dn < 8; ++dn)
#pragma unroll
        for (int r = 0; r < 4; ++r) oacc[dn][r] *= scl[r];
    }
    float rsum[4] = {0.f, 0.f, 0.f, 0.f};
#pragma unroll
    for (int nf = 0; nf < 8; ++nf)
#pragma unroll
      for (int r = 0; r < 4; ++r) {
        float pv = __expf(sacc[nf][r] - M[r]);
        sacc[nf][r] = pv;
        rsum[r] += pv;
      }
    {
      const int prow0 = wid * 16 + lq * 4;
#pragma unroll
      for (int nf = 0; nf < 8; ++nf)
#pragma unroll
        for (int r = 0; r < 4; ++r) {
          const int row = prow0 + r;
          *(unsigned short*)(Plb + row * 256 + (((nf * 16 + lr) * 2) ^ ((row & 7) << 4))) =
              f2bf(sacc[nf][r]);
        }
    }
#pragma unroll
    for (int r = 0; r < 4; ++r) {
      rsum[r] += __shfl_xor(rsum[r], 1);
      rsum[r] += __shfl_xor(rsum[r], 2);
      rsum[r] += __shfl_xor(rsum[r], 4);
      rsum[r] += __shfl_xor(rsum[r], 8);
      L[r] += rsum[r];
    }

    // own V(t) landed (KQ(t+1) 8 + stores 32 remain in flight)
    asm volatile("s_waitcnt vmcnt(40)" ::: "memory");
    __builtin_amdgcn_sched_barrier(0);

    __builtin_amdgcn_s_setprio(1);
#pragma unroll
    for (int kk = 0; kk < 4; ++kk) {
      const int prow = wid * 16 + lr;
      bf16x8 pf = *(const bf16x8*)(Plb + prow * 256 + ((kk * 64 + lq * 16) ^ ((prow & 7) << 4)));
#pragma unroll
      for (int dn = 0; dn < 8; ++dn) {
        const int vrow = dn * 16 + lr;
        bf16x8 vf = *(const bf16x8*)(Vlb + vrow * 256 + ((kk * 64 + lq * 16) ^ ((vrow & 7) << 4)));
        oacc[dn] = mfma_bf16(pf, vf, oacc[dn]);
      }
    }
    __builtin_amdgcn_s_setprio(0);

    __builtin_amdgcn_sched_barrier(0);
    __builtin_amdgcn_s_barrier();        // all waves done reading Vlb
    __builtin_amdgcn_sched_barrier(0);
#pragma unroll
    for (int p = 0; p < 4; ++p) gload_lds16(vsrc[p] + nv, Vlb + ldso[p]);
    __builtin_amdgcn_sched_barrier(0);
  }

  {
    const int qrow_base = b * 2048 + qi0 + wid * 16 + lq * 4;
#pragma unroll
    for (int dn = 0; dn < 8; ++dn)
#pragma unroll
      for (int r = 0; r < 4; ++r) {
        float v = oacc[dn][r] / L[r];
        ctx[(size_t)(qrow_base + r) * 1024 + bd * 128 + dn * 16 + lr] = f2bf(v);
      }
  }
}

// ---------------- launch ----------------

extern "C" void kernel_launch(void* const* d_in, const int* in_sizes, int n_in,
                              void* d_out, int out_size, void* d_ws, size_t ws_size,
                              hipStream_t stream) {
  const float* x  = (const float*)d_in[0];
  const float* Wq = (const float*)d_in[1];
  const float* bq = (const float*)d_in[2];
  const float* Wk = (const float*)d_in[3];
  const float* bk = (const float*)d_in[4];
  const float* Wv = (const float*)d_in[5];
  const float* bv = (const float*)d_in[6];
  const float* Wo = (const float*)d_in[7];
  const float* bo = (const float*)d_in[8];
  const float* er = (const float*)d_in[9];

  char* ws = (char*)d_ws;
  unsigned short* xb  = (unsigned short*)(ws + 0);          //  8 MB
  unsigned short* Wqb = (unsigned short*)(ws + 8388608);    //  2 MB
  unsigned short* Wkb = (unsigned short*)(ws + 10485760);   //  2 MB
  unsigned short* Wvb = (unsigned short*)(ws + 12582912);   //  2 MB
  unsigned short* Wob = (unsigned short*)(ws + 14680064);   //  2 MB
  unsigned short* Qb  = (unsigned short*)(ws + 16777216);   //  8 MB
  unsigned short* Kb  = (unsigned short*)(ws + 25165824);   //  8 MB
  unsigned short* Vtb = (unsigned short*)(ws + 33554432);   //  8 MB [16][128][2048]
  unsigned short* ctx = (unsigned short*)(ws + 41943040);   //  8 MB
  unsigned short* ert = (unsigned short*)(ws + 50331648);   //  0.5 MB [2048][128]

  float* a_out = (float*)d_out + 4194304;

  cvt_f32_bf16<<<dim3(4096), dim3(256), 0, stream>>>(x, xb, 1048576);
  cvt4_f32_bf16<<<dim3(4096), dim3(256), 0, stream>>>(Wq, Wk, Wv, Wo, Wqb, Wkb, Wvb, Wob);
  er_transpose<<<dim3(64, 4), dim3(32, 8), 0, stream>>>(er, ert);

  gemm_qkv3<<<dim3(32, 8), dim3(512), 0, stream>>>(xb, Wqb, Wkb, Wvb, bq, bk, bv,
                                                   Qb, Kb, Vtb);

  attn_fused<<<dim3(16, 16), dim3(512), 0, stream>>>(Qb, Kb, Vtb, ert, a_out, ctx);

  gemm_bt<<<dim3(32, 8), dim3(256), 0, stream>>>(ctx, Wob, bo, (float*)d_out);
}

// Round 18
// 171.089 us; speedup vs baseline: 1.2366x; 1.0375x over previous
//
#include <hip/hip_runtime.h>

typedef __attribute__((ext_vector_type(8))) __bf16 bf16x8;
typedef __attribute__((ext_vector_type(4))) float f32x4;

__device__ __forceinline__ unsigned short f2bf(float f) {
  __bf16 h = (__bf16)f;
  return __builtin_bit_cast(unsigned short, h);
}

__device__ __forceinline__ f32x4 mfma_bf16(bf16x8 a, bf16x8 b, f32x4 c) {
  return __builtin_amdgcn_mfma_f32_16x16x32_bf16(a, b, c, 0, 0, 0);
}

__device__ __forceinline__ void gload_lds16(const void* g, void* l) {
  __builtin_amdgcn_global_load_lds((const __attribute__((address_space(1))) void*)g,
                                   (__attribute__((address_space(3))) void*)l, 16, 0, 0);
}

// ---------------- fused prep: x-cvt + 4-weight cvt + er transpose ----------------
// blocks [0,4096): x f32->bf16 ; [4096,8192): weights ; [8192,8448): er transpose

__global__ void prep_all(const float* __restrict__ x,
                         const float* __restrict__ Wq, const float* __restrict__ Wk,
                         const float* __restrict__ Wv, const float* __restrict__ Wo,
                         const float* __restrict__ er,
                         unsigned short* __restrict__ xb,
                         unsigned short* __restrict__ Wqb, unsigned short* __restrict__ Wkb,
                         unsigned short* __restrict__ Wvb, unsigned short* __restrict__ Wob,
                         unsigned short* __restrict__ ert)
{
  const int bid = blockIdx.x, tid = threadIdx.x;
  if (bid < 4096) {
    int i = bid * 256 + tid;
    float4 v = reinterpret_cast<const float4*>(x)[i];
    ushort4 o;
    o.x = f2bf(v.x); o.y = f2bf(v.y); o.z = f2bf(v.z); o.w = f2bf(v.w);
    reinterpret_cast<ushort4*>(xb)[i] = o;
  } else if (bid < 8192) {
    int i = (bid - 4096) * 256 + tid;            // 1048576 total
    int which = i >> 18, j = i & 262143;
    const float* src = (which == 0) ? Wq : (which == 1) ? Wk : (which == 2) ? Wv : Wo;
    unsigned short* dst = (which == 0) ? Wqb : (which == 1) ? Wkb : (which == 2) ? Wvb : Wob;
    float4 v = reinterpret_cast<const float4*>(src)[j];
    ushort4 o;
    o.x = f2bf(v.x); o.y = f2bf(v.y); o.z = f2bf(v.z); o.w = f2bf(v.w);
    reinterpret_cast<ushort4*>(dst)[j] = o;
  } else {
    __shared__ float t[32][33];
    int blk = bid - 8192;                        // 256 blocks: 64 w-tiles x 4 d-tiles
    int w0 = (blk & 63) * 32, d0 = (blk >> 6) * 32;
    int tx = tid & 31, ty = tid >> 5;            // 32 x 8
#pragma unroll
    for (int i = 0; i < 4; ++i)
      t[ty + i * 8][tx] = er[(size_t)(d0 + ty + i * 8) * 2048 + w0 + tx];
    __syncthreads();
#pragma unroll
    for (int i = 0; i < 4; ++i)
      ert[(size_t)(w0 + ty + i * 8) * 128 + d0 + tx] = f2bf(t[tx][ty + i * 8]);
  }
}

// ---------------- 3-in-1 QKV projection GEMM (R17 structure, verbatim) ----------------

__global__ __launch_bounds__(512, 1) void gemm_qkv3(
    const unsigned short* __restrict__ xb,
    const unsigned short* __restrict__ Wqb, const unsigned short* __restrict__ Wkb,
    const unsigned short* __restrict__ Wvb,
    const float* __restrict__ bq, const float* __restrict__ bk, const float* __restrict__ bvv,
    unsigned short* __restrict__ Qb, unsigned short* __restrict__ Kb,
    unsigned short* __restrict__ Vtb)
{
  __shared__ __align__(16) char lds[131072];   // buf: A@0 BQ@16K BK@32K BV@48K, x2

  const int tid = threadIdx.x;
  const int lane = tid & 63, wid = tid >> 6;
  const int lr = lane & 15, lq = lane >> 4;
  const int wr = wid >> 1, wc = wid & 1;       // 4M x 2N wave grid
  const int i0 = blockIdx.x * 128, j0 = blockIdx.y * 128;

  f32x4 aQ[2][4] = {}, aK[2][4] = {}, aV[2][4] = {};

  int ldso[2];
  const char *asrc[2], *qsrc[2], *ksrc[2], *vsrc[2];
#pragma unroll
  for (int p = 0; p < 2; ++p) {
    int L = p * 8192 + tid * 16;
    int row = L >> 7, colb = L & 127;
    int sc = colb ^ ((row & 7) << 4);
    ldso[p] = L;
    asrc[p] = (const char*)xb  + (size_t)(i0 + row) * 2048 + sc;
    qsrc[p] = (const char*)Wqb + (size_t)(j0 + row) * 2048 + sc;
    ksrc[p] = (const char*)Wkb + (size_t)(j0 + row) * 2048 + sc;
    vsrc[p] = (const char*)Wvb + (size_t)(j0 + row) * 2048 + sc;
  }

#pragma unroll
  for (int p = 0; p < 2; ++p) gload_lds16(asrc[p], lds + ldso[p]);
#pragma unroll
  for (int p = 0; p < 2; ++p) gload_lds16(qsrc[p], lds + 16384 + ldso[p]);
#pragma unroll
  for (int p = 0; p < 2; ++p) gload_lds16(ksrc[p], lds + 32768 + ldso[p]);
#pragma unroll
  for (int p = 0; p < 2; ++p) gload_lds16(vsrc[p], lds + 49152 + ldso[p]);

  const int swz = (lr & 7) << 4;

  for (int kt = 0; kt < 16; ++kt) {
    char* cb = lds + (kt & 1) * 65536;
    char* nb = lds + ((kt + 1) & 1) * 65536;

    asm volatile("s_waitcnt vmcnt(0)" ::: "memory");
    __builtin_amdgcn_sched_barrier(0);
    __builtin_amdgcn_s_barrier();
    __builtin_amdgcn_sched_barrier(0);

    if (kt < 15) {
      const int k0b = (kt + 1) * 128;
#pragma unroll
      for (int p = 0; p < 2; ++p) gload_lds16(asrc[p] + k0b, nb + ldso[p]);
#pragma unroll
      for (int p = 0; p < 2; ++p) gload_lds16(qsrc[p] + k0b, nb + 16384 + ldso[p]);
#pragma unroll
      for (int p = 0; p < 2; ++p) gload_lds16(ksrc[p] + k0b, nb + 32768 + ldso[p]);
#pragma unroll
      for (int p = 0; p < 2; ++p) gload_lds16(vsrc[p] + k0b, nb + 49152 + ldso[p]);
    }
    __builtin_amdgcn_sched_barrier(0);

#pragma unroll
    for (int kk = 0; kk < 2; ++kk) {
      const int coff = (kk * 64 + lq * 16) ^ swz;
      bf16x8 af[2];
#pragma unroll
      for (int m = 0; m < 2; ++m)
        af[m] = *(const bf16x8*)(cb + (wr * 32 + m * 16 + lr) * 128 + coff);
      bf16x8 bq_[4], bk_[4], bv_[4];
#pragma unroll
      for (int n = 0; n < 4; ++n) {
        const int rb = (wc * 64 + n * 16 + lr) * 128 + coff;
        bq_[n] = *(const bf16x8*)(cb + 16384 + rb);
        bk_[n] = *(const bf16x8*)(cb + 32768 + rb);
        bv_[n] = *(const bf16x8*)(cb + 49152 + rb);
      }
      __builtin_amdgcn_s_setprio(1);
#pragma unroll
      for (int m = 0; m < 2; ++m)
#pragma unroll
        for (int n = 0; n < 4; ++n) {
          aQ[m][n] = mfma_bf16(af[m], bq_[n], aQ[m][n]);
          aK[m][n] = mfma_bf16(af[m], bk_[n], aK[m][n]);
          aV[m][n] = mfma_bf16(af[m], bv_[n], aV[m][n]);
        }
      __builtin_amdgcn_s_setprio(0);
    }
  }

  float vbq[4], vbk[4], vbv[4];
#pragma unroll
  for (int n = 0; n < 4; ++n) {
    int gj = j0 + wc * 64 + n * 16 + lr;
    vbq[n] = bq[gj]; vbk[n] = bk[gj]; vbv[n] = bvv[gj];
  }

#pragma unroll
  for (int m = 0; m < 2; ++m)
#pragma unroll
    for (int n = 0; n < 4; ++n)
#pragma unroll
      for (int r = 0; r < 4; ++r) {
        int gi = i0 + wr * 32 + m * 16 + lq * 4 + r;
        int gj = j0 + wc * 64 + n * 16 + lr;
        Qb[(size_t)gi * 1024 + gj] = f2bf(aQ[m][n][r] + vbq[n]);
        Kb[(size_t)gi * 1024 + gj] = f2bf(aK[m][n][r] + vbk[n]);
      }

  __syncthreads();
  unsigned short* lds16 = (unsigned short*)lds;
#pragma unroll
  for (int m = 0; m < 2; ++m)
#pragma unroll
    for (int n = 0; n < 4; ++n)
#pragma unroll
      for (int r = 0; r < 4; ++r) {
        int il = wr * 32 + m * 16 + lq * 4 + r;
        int jl = wc * 64 + n * 16 + lr;
        lds16[jl * 132 + il] = f2bf(aV[m][n][r] + vbv[n]);
      }
  __syncthreads();
  {
    const int b = i0 >> 11, w0 = i0 & 2047, bd = j0 >> 7;
    for (int idx = tid; idx < 16384; idx += 512) {
      int dl = idx >> 7, wl = idx & 127;
      Vtb[(size_t)((b * 8 + bd) * 128 + dl) * 2048 + w0 + wl] = lds16[dl * 132 + wl];
    }
  }
}

// ---------------- Wo GEMM: qkv3-style 8-wave, swizzled 128B-row tiles ----------------
// Old 64B-row layout was an 8-way LDS bank conflict on every b128 fragment
// read (lanes 0-15 at lr*64 -> 2 bank groups). New layout: [128 rows][128B],
// XOR swizzle row&7 == lr&7 -> 2-way (free). 64KB dbuf -> 2 blocks/CU.

__global__ __launch_bounds__(512, 4) void gemm_bt(
    const unsigned short* __restrict__ A,
    const unsigned short* __restrict__ Bt,
    const float* __restrict__ bias,
    float* __restrict__ C)
{
  __shared__ __align__(16) char lds[65536];    // buf: A@0 B@16K, x2 @32K

  const int tid = threadIdx.x;
  const int lane = tid & 63, wid = tid >> 6;
  const int lr = lane & 15, lq = lane >> 4;
  const int wr = wid >> 1, wc = wid & 1;       // 4M x 2N wave grid
  const int i0 = blockIdx.x * 128, j0 = blockIdx.y * 128;

  f32x4 acc[2][4] = {};

  int ldso[2];
  const char *asrc[2], *bsrc[2];
#pragma unroll
  for (int p = 0; p < 2; ++p) {
    int L = p * 8192 + tid * 16;
    int row = L >> 7, colb = L & 127;
    int sc = colb ^ ((row & 7) << 4);
    ldso[p] = L;
    asrc[p] = (const char*)A  + (size_t)(i0 + row) * 2048 + sc;
    bsrc[p] = (const char*)Bt + (size_t)(j0 + row) * 2048 + sc;
  }

#pragma unroll
  for (int p = 0; p < 2; ++p) gload_lds16(asrc[p], lds + ldso[p]);
#pragma unroll
  for (int p = 0; p < 2; ++p) gload_lds16(bsrc[p], lds + 16384 + ldso[p]);

  const int swz = (lr & 7) << 4;

  for (int kt = 0; kt < 16; ++kt) {
    char* cb = lds + (kt & 1) * 32768;
    char* nb = lds + ((kt + 1) & 1) * 32768;

    asm volatile("s_waitcnt vmcnt(0)" ::: "memory");
    __builtin_amdgcn_sched_barrier(0);
    __builtin_amdgcn_s_barrier();
    __builtin_amdgcn_sched_barrier(0);

    if (kt < 15) {
      const int k0b = (kt + 1) * 128;
#pragma unroll
      for (int p = 0; p < 2; ++p) gload_lds16(asrc[p] + k0b, nb + ldso[p]);
#pragma unroll
      for (int p = 0; p < 2; ++p) gload_lds16(bsrc[p] + k0b, nb + 16384 + ldso[p]);
    }
    __builtin_amdgcn_sched_barrier(0);

#pragma unroll
    for (int kk = 0; kk < 2; ++kk) {
      const int coff = (kk * 64 + lq * 16) ^ swz;
      bf16x8 af[2];
#pragma unroll
      for (int m = 0; m < 2; ++m)
        af[m] = *(const bf16x8*)(cb + (wr * 32 + m * 16 + lr) * 128 + coff);
      bf16x8 bf_[4];
#pragma unroll
      for (int n = 0; n < 4; ++n)
        bf_[n] = *(const bf16x8*)(cb + 16384 + (wc * 64 + n * 16 + lr) * 128 + coff);
      __builtin_amdgcn_s_setprio(1);
#pragma unroll
      for (int m = 0; m < 2; ++m)
#pragma unroll
        for (int n = 0; n < 4; ++n)
          acc[m][n] = mfma_bf16(af[m], bf_[n], acc[m][n]);
      __builtin_amdgcn_s_setprio(0);
    }
  }

  float bv[4];
#pragma unroll
  for (int n = 0; n < 4; ++n) bv[n] = bias[j0 + wc * 64 + n * 16 + lr];
#pragma unroll
  for (int m = 0; m < 2; ++m)
#pragma unroll
    for (int n = 0; n < 4; ++n)
#pragma unroll
      for (int r = 0; r < 4; ++r) {
        int gi = i0 + wr * 32 + m * 16 + lq * 4 + r;
        int gj = j0 + wc * 64 + n * 16 + lr;
        C[(size_t)gi * 1024 + gj] = acc[m][n][r] + bv[n];
      }
}

// ---------------- fused attention (R15 structure, verbatim) ----------------

__global__ __launch_bounds__(512) void attn_fused(
    const unsigned short* __restrict__ Qb,
    const unsigned short* __restrict__ Kb,
    const unsigned short* __restrict__ Vt,
    const unsigned short* __restrict__ ErT,
    float* __restrict__ a_out,
    unsigned short* __restrict__ ctx)
{
  __shared__ __align__(16) char Klb[32768];  // K[kj] [128][256B] swz
  __shared__ __align__(16) char Qlb[32768];  // Q[kj] [128][256B] swz
  __shared__ __align__(16) char Vlb[32768];  // Vt    [128][256B] swz
  __shared__ __align__(16) char Plb[32768];  // P     [128][256B] swz

  const int bb = blockIdx.x;                 // b*8+band
  const int bd = bb & 7, b = bb >> 3;
  const int qi0 = blockIdx.y * 128;
  const int tid = threadIdx.x, wid = tid >> 6, lane = tid & 63;
  const int lr = lane & 15, lq = lane >> 4;

  bf16x8 qf[4], ef[4];
  {
    const unsigned short* Qrow = Qb + (size_t)(b * 2048 + qi0 + wid * 16 + lr) * 1024 + bd * 128;
    const unsigned short* Erow = ErT + (size_t)(qi0 + wid * 16 + lr) * 128;
#pragma unroll
    for (int kk = 0; kk < 4; ++kk) {
      qf[kk] = *(const bf16x8*)(Qrow + kk * 32 + lq * 8);
      ef[kk] = *(const bf16x8*)(Erow + kk * 32 + lq * 8);
    }
  }

  int ldso[4];
  const char *ksrc[4], *qsrc[4], *vsrc[4];
#pragma unroll
  for (int p = 0; p < 4; ++p) {
    int L = p * 8192 + tid * 16;
    int row = L >> 8, cs = L & 255;
    int sc = cs ^ ((row & 7) << 4);
    ldso[p] = L;
    ksrc[p] = (const char*)Kb + ((size_t)(b * 2048 + row) * 1024 + bd * 128) * 2 + sc;
    qsrc[p] = (const char*)Qb + ((size_t)(b * 2048 + row) * 1024 + bd * 128) * 2 + sc;
    vsrc[p] = (const char*)Vt + ((size_t)(bb * 128 + row) * 2048) * 2 + sc;
  }

  // prologue: stage tile 0, drain everything once (iter-0 safety)
#pragma unroll
  for (int p = 0; p < 4; ++p) gload_lds16(ksrc[p], Klb + ldso[p]);
#pragma unroll
  for (int p = 0; p < 4; ++p) gload_lds16(qsrc[p], Qlb + ldso[p]);
#pragma unroll
  for (int p = 0; p < 4; ++p) gload_lds16(vsrc[p], Vlb + ldso[p]);
  asm volatile("s_waitcnt vmcnt(0)" ::: "memory");
  __builtin_amdgcn_sched_barrier(0);

  f32x4 oacc[8] = {};
  float M[4], L[4];
#pragma unroll
  for (int r = 0; r < 4; ++r) { M[r] = -1e30f; L[r] = 0.f; }

  float* abase = a_out + (size_t)bb * 2048 * 2048;

  for (int kt = 0; kt < 16; ++kt) {
    const int kj0 = kt * 128;
    const size_t nkq = (size_t)((kt + 1) & 15) * 262144;
    const size_t nv = (size_t)((kt + 1) & 15) * 256;

    // own KQ(t) landed (32 stores + 4 V may remain in flight); rendezvous
    asm volatile("s_waitcnt vmcnt(36)" ::: "memory");
    __builtin_amdgcn_sched_barrier(0);
    __builtin_amdgcn_s_barrier();
    __builtin_amdgcn_sched_barrier(0);

    f32x4 sacc[8] = {};
    __builtin_amdgcn_s_setprio(1);
#pragma unroll
    for (int kk = 0; kk < 4; ++kk) {
#pragma unroll
      for (int nf = 0; nf < 8; ++nf) {
        const int row = nf * 16 + lr;
        bf16x8 kf = *(const bf16x8*)(Klb + row * 256 + ((kk * 64 + lq * 16) ^ ((row & 7) << 4)));
        sacc[nf] = mfma_bf16(qf[kk], kf, sacc[nf]);
      }
#pragma unroll
      for (int nf = 0; nf < 8; ++nf) {
        const int row = nf * 16 + lr;
        bf16x8 qkf = *(const bf16x8*)(Qlb + row * 256 + ((kk * 64 + lq * 16) ^ ((row & 7) << 4)));
        sacc[nf] = mfma_bf16(ef[kk], qkf, sacc[nf]);
      }
    }
    __builtin_amdgcn_s_setprio(0);

    __builtin_amdgcn_sched_barrier(0);
    __builtin_amdgcn_s_barrier();        // all waves done reading Klb/Qlb
    __builtin_amdgcn_sched_barrier(0);

    // issue KQ(t+1) FIRST (keeps stores younger in FIFO)
#pragma unroll
    for (int p = 0; p < 4; ++p) gload_lds16(ksrc[p] + nkq, Klb + ldso[p]);
#pragma unroll
    for (int p = 0; p < 4; ++p) gload_lds16(qsrc[p] + nkq, Qlb + ldso[p]);
    __builtin_amdgcn_sched_barrier(0);

    // scale and emit `a` (never waited on mid-loop)
#pragma unroll
    for (int nf = 0; nf < 8; ++nf)
#pragma unroll
      for (int r = 0; r < 4; ++r) sacc[nf][r] *= 0.03125f;
    {
      const int qrow_base = qi0 + wid * 16 + lq * 4;
#pragma unroll
      for (int nf = 0; nf < 8; ++nf)
#pragma unroll
        for (int r = 0; r < 4; ++r)
          abase[(size_t)(qrow_base + r) * 2048 + kj0 + nf * 16 + lr] = sacc[nf][r];
    }
    __builtin_amdgcn_sched_barrier(0);

    float rmax[4];
#pragma unroll
    for (int r = 0; r < 4; ++r) {
      float m0 = sacc[0][r];
#pragma unroll
      for (int nf = 1; nf < 8; ++nf) m0 = fmaxf(m0, sacc[nf][r]);
      m0 = fmaxf(m0, __shfl_xor(m0, 1));
      m0 = fmaxf(m0, __shfl_xor(m0, 2));
      m0 = fmaxf(m0, __shfl_xor(m0, 4));
      m0 = fmaxf(m0, __shfl_xor(m0, 8));
      rmax[r] = m0;
    }
    bool small = (rmax[0] - M[0] <= 8.f) & (rmax[1] - M[1] <= 8.f) &
                 (rmax[2] - M[2] <= 8.f) & (rmax[3] - M[3] <= 8.f);
    unsigned long long vote = __ballot(small);
    if (vote != ~0ull) {
      float scl[4];
#pragma unroll
      for (int r = 0; r < 4; ++r) {
        float Mn = fmaxf(M[r], rmax[r]);
        scl[r] = __expf(M[r] - Mn);
        M[r] = Mn;
        L[r] *= scl[r];
      }
#pragma unroll
      for (int dn = 0; dn < 8; ++dn)
#pragma unroll
        for (int r = 0; r < 4; ++r) oacc[dn][r] *= scl[r];
    }
    float rsum[4] = {0.f, 0.f, 0.f, 0.f};
#pragma unroll
    for (int nf = 0; nf < 8; ++nf)
#pragma unroll
      for (int r = 0; r < 4; ++r) {
        float pv = __expf(sacc[nf][r] - M[r]);
        sacc[nf][r] = pv;
        rsum[r] += pv;
      }
    {
      const int prow0 = wid * 16 + lq * 4;
#pragma unroll
      for (int nf = 0; nf < 8; ++nf)
#pragma unroll
        for (int r = 0; r < 4; ++r) {
          const int row = prow0 + r;
          *(unsigned short*)(Plb + row * 256 + (((nf * 16 + lr) * 2) ^ ((row & 7) << 4))) =
              f2bf(sacc[nf][r]);
        }
    }
#pragma unroll
    for (int r = 0; r < 4; ++r) {
      rsum[r] += __shfl_xor(rsum[r], 1);
      rsum[r] += __shfl_xor(rsum[r], 2);
      rsum[r] += __shfl_xor(rsum[r], 4);
      rsum[r] += __shfl_xor(rsum[r], 8);
      L[r] += rsum[r];
    }

    // own V(t) landed (KQ(t+1) 8 + stores 32 remain in flight)
    asm volatile("s_waitcnt vmcnt(40)" ::: "memory");
    __builtin_amdgcn_sched_barrier(0);

    __builtin_amdgcn_s_setprio(1);
#pragma unroll
    for (int kk = 0; kk < 4; ++kk) {
      const int prow = wid * 16 + lr;
      bf16x8 pf = *(const bf16x8*)(Plb + prow * 256 + ((kk * 64 + lq * 16) ^ ((prow & 7) << 4)));
#pragma unroll
      for (int dn = 0; dn < 8; ++dn) {
        const int vrow = dn * 16 + lr;
        bf16x8 vf = *(const bf16x8*)(Vlb + vrow * 256 + ((kk * 64 + lq * 16) ^ ((vrow & 7) << 4)));
        oacc[dn] = mfma_bf16(pf, vf, oacc[dn]);
      }
    }
    __builtin_amdgcn_s_setprio(0);

    __builtin_amdgcn_sched_barrier(0);
    __builtin_amdgcn_s_barrier();        // all waves done reading Vlb
    __builtin_amdgcn_sched_barrier(0);
#pragma unroll
    for (int p = 0; p < 4; ++p) gload_lds16(vsrc[p] + nv, Vlb + ldso[p]);
    __builtin_amdgcn_sched_barrier(0);
  }

  {
    const int qrow_base = b * 2048 + qi0 + wid * 16 + lq * 4;
#pragma unroll
    for (int dn = 0; dn < 8; ++dn)
#pragma unroll
      for (int r = 0; r < 4; ++r) {
        float v = oacc[dn][r] / L[r];
        ctx[(size_t)(qrow_base + r) * 1024 + bd * 128 + dn * 16 + lr] = f2bf(v);
      }
  }
}

// ---------------- launch ----------------

extern "C" void kernel_launch(void* const* d_in, const int* in_sizes, int n_in,
                              void* d_out, int out_size, void* d_ws, size_t ws_size,
                              hipStream_t stream) {
  const float* x  = (const float*)d_in[0];
  const float* Wq = (const float*)d_in[1];
  const float* bq = (const float*)d_in[2];
  const float* Wk = (const float*)d_in[3];
  const float* bk = (const float*)d_in[4];
  const float* Wv = (const float*)d_in[5];
  const float* bv = (const float*)d_in[6];
  const float* Wo = (const float*)d_in[7];
  const float* bo = (const float*)d_in[8];
  const float* er = (const float*)d_in[9];

  char* ws = (char*)d_ws;
  unsigned short* xb  = (unsigned short*)(ws + 0);          //  8 MB
  unsigned short* Wqb = (unsigned short*)(ws + 8388608);    //  2 MB
  unsigned short* Wkb = (unsigned short*)(ws + 10485760);   //  2 MB
  unsigned short* Wvb = (unsigned short*)(ws + 12582912);   //  2 MB
  unsigned short* Wob = (unsigned short*)(ws + 14680064);   //  2 MB
  unsigned short* Qb  = (unsigned short*)(ws + 16777216);   //  8 MB
  unsigned short* Kb  = (unsigned short*)(ws + 25165824);   //  8 MB
  unsigned short* Vtb = (unsigned short*)(ws + 33554432);   //  8 MB [16][128][2048]
  unsigned short* ctx = (unsigned short*)(ws + 41943040);   //  8 MB
  unsigned short* ert = (unsigned short*)(ws + 50331648);   //  0.5 MB [2048][128]

  float* a_out = (float*)d_out + 4194304;

  prep_all<<<dim3(8448), dim3(256), 0, stream>>>(x, Wq, Wk, Wv, Wo, er,
                                                 xb, Wqb, Wkb, Wvb, Wob, ert);

  gemm_qkv3<<<dim3(32, 8), dim3(512), 0, stream>>>(xb, Wqb, Wkb, Wvb, bq, bk, bv,
                                                   Qb, Kb, Vtb);

  attn_fused<<<dim3(16, 16), dim3(512), 0, stream>>>(Qb, Kb, Vtb, ert, a_out, ctx);

  gemm_bt<<<dim3(32, 8), dim3(512), 0, stream>>>(ctx, Wob, bo, (float*)d_out);
}